// Round 9
// baseline (1372.757 us; speedup 1.0000x reference)
//
#include <hip/hip_runtime.h>
#include <hip/hip_bf16.h>
#include <math.h>

#define B_ 16
#define CIN_ 15
#define C_ 64
#define L_ 4

typedef __attribute__((ext_vector_type(8))) short short8;
typedef __attribute__((ext_vector_type(4))) short short4v;
typedef __attribute__((ext_vector_type(4))) float f32x4;

// Fast exact-GELU: erf via Abramowitz-Stegun 7.1.26 (|eps| <= 1.5e-7), branchless.
__device__ __forceinline__ float gelu_f(float x) {
    float z = fabsf(x) * 0.70710678118654752440f;
    float t = __builtin_amdgcn_rcpf(fmaf(0.3275911f, z, 1.0f));
    float p = t * fmaf(t, fmaf(t, fmaf(t, fmaf(t, 1.061405429f, -1.453152027f), 1.421413741f), -0.284496736f), 0.254829592f);
    float e = __expf(-z * z);
    float E = fmaf(-p, e, 1.0f);
    return 0.5f * fmaf(fabsf(x), E, x);
}

__device__ __forceinline__ unsigned short f2bf(float x) {
    __hip_bfloat16 h = __float2bfloat16(x);
    return *(unsigned short*)&h;
}
__device__ __forceinline__ float bf2f(unsigned short u) {
    __hip_bfloat16 h = *(__hip_bfloat16*)&u;
    return __bfloat162float(h);
}
__device__ __forceinline__ f32x4 mfma16(short8 a, short8 b, f32x4 c) {
    return __builtin_amdgcn_mfma_f32_16x16x32_bf16(a, b, c, 0, 0, 0);
}

#define TWO_PI_OVER_256 0.024543692606170259674f

// ---------------- one-time prep: split tables & weights into bf16 hi/lo ----------------
__global__ __launch_bounds__(256) void k_prep(const float* __restrict__ skip_w,
                                              const float* __restrict__ bn_g, const float* __restrict__ bn_v,
                                              const float* __restrict__ proj_w, const float* __restrict__ lift_w,
                                              unsigned short* __restrict__ TfH, unsigned short* __restrict__ TfL,
                                              unsigned short* __restrict__ TiH, unsigned short* __restrict__ TiL,
                                              unsigned short* __restrict__ WH, unsigned short* __restrict__ WL,
                                              unsigned short* __restrict__ PH, unsigned short* __restrict__ PL,
                                              unsigned short* __restrict__ FcH, unsigned short* __restrict__ FcL,
                                              unsigned short* __restrict__ FsH, unsigned short* __restrict__ FsL,
                                              unsigned short* __restrict__ FnH, unsigned short* __restrict__ FnL,
                                              unsigned short* __restrict__ IcH, unsigned short* __restrict__ IcL,
                                              unsigned short* __restrict__ IsH, unsigned short* __restrict__ IsL,
                                              unsigned short* __restrict__ InH, unsigned short* __restrict__ InL,
                                              unsigned short* __restrict__ LwH, unsigned short* __restrict__ LwL) {
    int id = blockIdx.x * 256 + threadIdx.x;
    if (id < 8192) {
        int col = id >> 8, w = id & 255;
        int kk = (col < 16) ? col : (col - 16);
        float s, c;
        sincosf(TWO_PI_OVER_256 * (float)((w * kk) & 255), &s, &c);
        float v = (col < 16) ? c : -s;
        unsigned short hi = f2bf(v);
        TfH[id] = hi; TfL[id] = f2bf(v - bf2f(hi));
    } else if (id < 16384) {
        int idx = id - 8192;
        int w = idx >> 5, k = idx & 31, ky = k >> 1;
        float s, c;
        sincosf(TWO_PI_OVER_256 * (float)((w * ky) & 255), &s, &c);
        float v = (k & 1) ? -s : c;
        unsigned short hi = f2bf(v);
        TiH[idx] = hi; TiL[idx] = f2bf(v - bf2f(hi));
    } else if (id < 32768) {
        int idx = id - 16384;
        int lco = idx >> 6;
        float scl = bn_g[lco] * rsqrtf(bn_v[lco] + 1e-5f);
        float v = scl * skip_w[idx];
        unsigned short hi = f2bf(v);
        WH[idx] = hi; WL[idx] = f2bf(v - bf2f(hi));
    } else if (id < 36864) {
        int idx = id - 32768;
        float v = proj_w[idx];
        unsigned short hi = f2bf(v);
        PH[idx] = hi; PL[idx] = f2bf(v - bf2f(hi));
    } else if (id < 45056) {
        int idx = id - 36864;          // fwd tables [j=32][h=256]
        int j = idx >> 8, h = idx & 255;
        int kxu = j + ((j < 16) ? 0 : 224);
        float s, c;
        sincosf(TWO_PI_OVER_256 * (float)((h * kxu) & 255), &s, &c);
        unsigned short ch = f2bf(c);
        FcH[idx] = ch; FcL[idx] = f2bf(c - bf2f(ch));
        unsigned short sh = f2bf(s);
        unsigned short sl = f2bf(s - bf2f(sh));
        FsH[idx] = sh; FsL[idx] = sl;
        FnH[idx] = sh ^ 0x8000; FnL[idx] = sl ^ 0x8000;   // exact negation in bf16
    } else if (id < 53248) {
        int idx = id - 45056;          // inv tables [h=256][j=32]
        int h = idx >> 5, j = idx & 31;
        int kxu = j + ((j < 16) ? 0 : 224);
        float s, c;
        sincosf(TWO_PI_OVER_256 * (float)((h * kxu) & 255), &s, &c);
        unsigned short ch = f2bf(c);
        IcH[idx] = ch; IcL[idx] = f2bf(c - bf2f(ch));
        unsigned short sh = f2bf(s);
        unsigned short sl = f2bf(s - bf2f(sh));
        IsH[idx] = sh; IsL[idx] = sl;
        InH[idx] = sh ^ 0x8000; InL[idx] = sl ^ 0x8000;
    } else if (id < 55296) {
        int idx = id - 53248;          // lift weights [co=64][k=32] (k>=15 zero-padded)
        int co = idx >> 5, k = idx & 31;
        float v = (k < CIN_) ? lift_w[co * CIN_ + k] : 0.0f;
        unsigned short hi = f2bf(v);
        LwH[idx] = hi; LwL[idx] = f2bf(v - bf2f(hi));
    }
}

// ---------------- lift conv1x1 (15->64) via MFMA + GELU + fused forward w-DFT ----------------
// C-SPLIT for occupancy: 8192 blocks, each (b, h, c-half of 32). LDS ~17KB -> 8 blocks/CU.
// X layout [b][h][c][w]: each block writes a contiguous 16KB half-stream.
__global__ __launch_bounds__(256) void k_lift(const float* __restrict__ g,
                                              const unsigned short* __restrict__ LwH, const unsigned short* __restrict__ LwL,
                                              const float* __restrict__ lb, unsigned short* __restrict__ X,
                                              const unsigned short* __restrict__ TfH, const unsigned short* __restrict__ TfL,
                                              float2* __restrict__ Y) {
    __shared__ unsigned short xl[32 * 264];
    __shared__ float lbs[C_];
    int b = blockIdx.x >> 9, h = (blockIdx.x >> 1) & 255, ch = blockIdx.x & 1;
    int t = threadIdx.x;
    if (t < C_) lbs[t] = lb[t];
    int wv = t >> 6, ln = t & 63;
    int lx = ln & 15, q = ln >> 4;
    int cob = ch * 32;
    // B-frags: col co = cob + mt*16+lx, k = q*8+j
    short8 bwh[2], bwl[2];
    #pragma unroll
    for (int mt = 0; mt < 2; mt++) {
        bwh[mt] = *(const short8*)(LwH + (cob + mt * 16 + lx) * 32 + q * 8);
        bwl[mt] = *(const short8*)(LwL + (cob + mt * 16 + lx) * 32 + q * 8);
    }
    __syncthreads();
    const float* gb = g + ((size_t)(b * CIN_) * 256 + h) * 256;  // + ci*65536 + w
    #pragma unroll 1
    for (int nt = 0; nt < 4; nt++) {
        int w0 = wv * 64 + nt * 16;
        int w = w0 + lx;
        // A-frag: row = w (lane lx), k = ci = q*8+j  (zero for ci >= 15)
        short8 agh = {0, 0, 0, 0, 0, 0, 0, 0};
        short8 agl = {0, 0, 0, 0, 0, 0, 0, 0};
        #pragma unroll
        for (int j = 0; j < 8; j++) {
            int ci = q * 8 + j;
            if (ci < CIN_) {
                float v = gb[(size_t)ci * 65536 + w];
                unsigned short hv = f2bf(v);
                agh[j] = (short)hv;
                agl[j] = (short)f2bf(v - bf2f(hv));
            }
        }
        f32x4 acc[2];
        #pragma unroll
        for (int mt = 0; mt < 2; mt++) acc[mt] = (f32x4){0.f, 0.f, 0.f, 0.f};
        #pragma unroll
        for (int mt = 0; mt < 2; mt++) {
            acc[mt] = mfma16(agh, bwh[mt], acc[mt]);
            acc[mt] = mfma16(agh, bwl[mt], acc[mt]);
            acc[mt] = mfma16(agl, bwh[mt], acc[mt]);
        }
        // epilogue: xl = gelu(D + bias), b64 vectorized (lane holds w = w0+q*4+r, c_local = mt*16+lx)
        #pragma unroll
        for (int mt = 0; mt < 2; mt++) {
            int cl = mt * 16 + lx;
            float bias = lbs[cob + cl];
            short4v nw;
            #pragma unroll
            for (int r = 0; r < 4; r++)
                nw[r] = (short)f2bf(gelu_f(acc[mt][r] + bias));
            *(short4v*)(&xl[cl * 264 + w0 + q * 4]) = nw;
        }
    }
    __syncthreads();
    // forward w-DFT: 32 c-rows handled by waves 0,1 (A-row = lane&15 fixes 16 rows/wave)
    if (wv < 2) {
        f32x4 fa0 = {0.f, 0.f, 0.f, 0.f}, fa1 = {0.f, 0.f, 0.f, 0.f};
        for (int ks = 0; ks < 8; ks++) {
            int k0 = ks * 32;
            short8 a = *(const short8*)(&xl[(wv * 16 + lx) * 264 + k0 + q * 8]);
            short8 bh0 = *(const short8*)(TfH + lx * 256 + k0 + q * 8);
            short8 bl0 = *(const short8*)(TfL + lx * 256 + k0 + q * 8);
            short8 bh1 = *(const short8*)(TfH + (16 + lx) * 256 + k0 + q * 8);
            short8 bl1 = *(const short8*)(TfL + (16 + lx) * 256 + k0 + q * 8);
            fa0 = mfma16(a, bh0, fa0); fa0 = mfma16(a, bl0, fa0);
            fa1 = mfma16(a, bh1, fa1); fa1 = mfma16(a, bl1, fa1);
        }
        #pragma unroll
        for (int r = 0; r < 4; r++) {
            int c = cob + wv * 16 + q * 4 + r;
            Y[(b * 64 + c) * 4096 + h * 16 + lx] = make_float2(fa0[r], fa1[r]);
        }
    }
    // contiguous 16KB X half-write: X[b][h][c][w]
    unsigned short* Xg = X + (size_t)(b * 256 + h) * 16384 + ch * 8192;
    #pragma unroll
    for (int r = 0; r < 4; r++) {
        int idx = r * 256 + t;
        int c = idx >> 5, w8 = idx & 31;
        *(short8*)(Xg + idx * 8) = *(const short8*)(&xl[c * 264 + w8 * 8]);
    }
}

// ---------------- forward partial DFT over h — MFMA version + FUSED weight repack ----------------
// Repack for this layer rides in the latency shadow: block bc also moves (j=bc>>5, i=(bc&31)*2 +{0,1})
// of WPK. k_mix (launched after on the same stream) is the only WPK consumer -> ordering safe.
__global__ __launch_bounds__(256) void k_fwd_h(const float2* __restrict__ Y, float2* __restrict__ XF,
                                               const unsigned short* __restrict__ FcH, const unsigned short* __restrict__ FcL,
                                               const unsigned short* __restrict__ FsH, const unsigned short* __restrict__ FsL,
                                               const unsigned short* __restrict__ FnH, const unsigned short* __restrict__ FnL,
                                               const float* __restrict__ w1r, const float* __restrict__ w1i,
                                               const float* __restrict__ w2r, const float* __restrict__ w2i,
                                               float2* __restrict__ WPK, int l) {
    __shared__ float red[4][2][2][64][4];   // [wave][rowtile][R/I][lane][reg] = 16 KB
    int bc = blockIdx.x;
    int t = threadIdx.x;
    int wv = t >> 6, lid = t & 63, lx = lid & 15, g = lid >> 4;
    const float2* Yb = Y + (size_t)bc * 4096;
    f32x4 aR[2], aI[2];
    aR[0] = (f32x4){0.f,0.f,0.f,0.f}; aR[1] = aR[0]; aI[0] = aR[0]; aI[1] = aR[0];
    #pragma unroll
    for (int kk = 0; kk < 2; kk++) {
        int ks = wv * 2 + kk;
        short8 yrh, yrl, yih, yil;
        #pragma unroll
        for (int j = 0; j < 8; j++) {
            float2 v = Yb[(ks * 32 + g * 8 + j) * 16 + lx];
            unsigned short h1 = f2bf(v.x);
            yrh[j] = (short)h1; yrl[j] = (short)f2bf(v.x - bf2f(h1));
            unsigned short h2 = f2bf(v.y);
            yih[j] = (short)h2; yil[j] = (short)f2bf(v.y - bf2f(h2));
        }
        #pragma unroll
        for (int rt = 0; rt < 2; rt++) {
            int base = (rt * 16 + lx) * 256 + ks * 32 + g * 8;
            short8 ch = *(const short8*)(FcH + base);
            short8 cl = *(const short8*)(FcL + base);
            short8 sh = *(const short8*)(FsH + base);
            short8 sl = *(const short8*)(FsL + base);
            short8 nh = *(const short8*)(FnH + base);
            short8 nl = *(const short8*)(FnL + base);
            // re = cos.Yr + sin.Yi ; im = cos.Yi - sin.Yr
            aR[rt] = mfma16(ch, yrh, aR[rt]);
            aR[rt] = mfma16(ch, yrl, aR[rt]);
            aR[rt] = mfma16(cl, yrh, aR[rt]);
            aR[rt] = mfma16(sh, yih, aR[rt]);
            aR[rt] = mfma16(sh, yil, aR[rt]);
            aR[rt] = mfma16(sl, yih, aR[rt]);
            aI[rt] = mfma16(ch, yih, aI[rt]);
            aI[rt] = mfma16(ch, yil, aI[rt]);
            aI[rt] = mfma16(cl, yih, aI[rt]);
            aI[rt] = mfma16(nh, yrh, aI[rt]);
            aI[rt] = mfma16(nh, yrl, aI[rt]);
            aI[rt] = mfma16(nl, yrh, aI[rt]);
        }
    }
    #pragma unroll
    for (int rt = 0; rt < 2; rt++) {
        *(f32x4*)&red[wv][rt][0][lid][0] = aR[rt];
        *(f32x4*)&red[wv][rt][1][lid][0] = aI[rt];
    }
    // ---- fused repack (independent; loads overlap the barrier wait) ----
    {
        int j = bc >> 5;            // 0..31
        int i2 = (bc & 31) * 2;     // 0,2,...,62
        int ky = t & 15, o0 = (t >> 4) * 4;
        int x = j & 15;
        const float* wr = (j < 16) ? w1r : w2r;
        const float* wi = (j < 16) ? w1i : w2i;
        #pragma unroll
        for (int ii = 0; ii < 2; ii++) {
            int i = i2 + ii;
            size_t sb = ((size_t)(l * 64 + i) * 64 + o0) * 256 + x * 16 + ky;
            float r0 = wr[sb];       float v0 = wi[sb];
            float r1 = wr[sb + 256]; float v1 = wi[sb + 256];
            float r2 = wr[sb + 512]; float v2 = wi[sb + 512];
            float r3 = wr[sb + 768]; float v3 = wi[sb + 768];
            float4* dst = (float4*)(WPK + ((size_t)(j * 16 + ky) * 64 + i) * 64 + o0);
            dst[0] = make_float4(r0, v0, r1, v1);
            dst[1] = make_float4(r2, v2, r3, v3);
        }
    }
    __syncthreads();
    if (t < 128) {
        int rt = t >> 6, ll = t & 63;
        int llx = ll & 15, gg = ll >> 4;
        f32x4 R = *(const f32x4*)&red[0][rt][0][ll][0];
        f32x4 I = *(const f32x4*)&red[0][rt][1][ll][0];
        #pragma unroll
        for (int w = 1; w < 4; w++) {
            R += *(const f32x4*)&red[w][rt][0][ll][0];
            I += *(const f32x4*)&red[w][rt][1][ll][0];
        }
        #pragma unroll
        for (int r = 0; r < 4; r++) {
            int j = rt * 16 + gg * 4 + r;
            XF[(j * 16 + llx) * 1024 + bc] = make_float2(R[r], I[r]);
        }
    }
}

// ---------------- mode mix: W tile staged in LDS ----------------
__global__ __launch_bounds__(256) void k_mix(const float2* __restrict__ XF, const float2* __restrict__ WPK,
                                             float2* __restrict__ YF) {
    __shared__ float2 xs[1024];
    __shared__ float2 wls[4096];
    int s = blockIdx.x;
    int t = threadIdx.x;
    for (int idx = t; idx < 1024; idx += 256) xs[idx] = XF[s * 1024 + idx];
    for (int idx = t; idx < 4096; idx += 256) wls[idx] = WPK[(size_t)s * 4096 + idx];
    __syncthreads();
    int o = t & 63, bg = t >> 6;
    float2 acc[4];
    #pragma unroll
    for (int q = 0; q < 4; q++) acc[q] = make_float2(0.f, 0.f);
    for (int i = 0; i < 64; i++) {
        float2 wv = wls[i * 64 + o];
        #pragma unroll
        for (int q = 0; q < 4; q++) {
            float2 xv = xs[(bg * 4 + q) * 64 + i];
            acc[q].x += xv.x * wv.x - xv.y * wv.y;
            acc[q].y += xv.x * wv.y + xv.y * wv.x;
        }
    }
    #pragma unroll
    for (int q = 0; q < 4; q++) {
        int b = bg * 4 + q;
        YF[(b * 64 + o) * 512 + s] = acc[q];
    }
}

// ---------------- inverse DFT over kx — MFMA, emits PRE-SCALED, PRE-SPLIT bf16 hi/lo Z ----------------
__global__ __launch_bounds__(256) void k_inv_h(const float2* __restrict__ YF, unsigned short* __restrict__ Zs,
                                               const unsigned short* __restrict__ IcH, const unsigned short* __restrict__ IcL,
                                               const unsigned short* __restrict__ IsH, const unsigned short* __restrict__ IsL,
                                               const unsigned short* __restrict__ InH, const unsigned short* __restrict__ InL,
                                               const float* __restrict__ bng, const float* __restrict__ bnv) {
    int bc = blockIdx.x;
    int t = threadIdx.x;
    int wv = t >> 6, l = t & 63, lx = l & 15, g = l >> 4;
    const float2* Yb = YF + (size_t)bc * 512;
    short8 xrh, xrl, xih, xil;
    #pragma unroll
    for (int jj = 0; jj < 8; jj++) {
        float2 v = Yb[(g * 8 + jj) * 16 + lx];
        unsigned short h1 = f2bf(v.x);
        xrh[jj] = (short)h1; xrl[jj] = (short)f2bf(v.x - bf2f(h1));
        unsigned short h2 = f2bf(v.y);
        xih[jj] = (short)h2; xil[jj] = (short)f2bf(v.y - bf2f(h2));
    }
    int c = bc & 63;
    float s = bng[c] * rsqrtf(bnv[c] + 1e-5f) * ((lx == 0) ? (1.0f / 65536.0f) : (2.0f / 65536.0f));
    unsigned short* Zb = Zs + (size_t)bc * 16384;
    #pragma unroll
    for (int hh = 0; hh < 4; hh++) {
        int ht = wv * 4 + hh;
        int base = (ht * 16 + lx) * 32 + g * 8;
        short8 ch = *(const short8*)(IcH + base);
        short8 cl = *(const short8*)(IcL + base);
        short8 sh = *(const short8*)(IsH + base);
        short8 sl = *(const short8*)(IsL + base);
        short8 nh = *(const short8*)(InH + base);
        short8 nl = *(const short8*)(InL + base);
        f32x4 aR = {0.f,0.f,0.f,0.f}, aI = {0.f,0.f,0.f,0.f};
        // zr = cos.Xr - sin.Xi ; zi = sin.Xr + cos.Xi
        aR = mfma16(ch, xrh, aR); aR = mfma16(ch, xrl, aR); aR = mfma16(cl, xrh, aR);
        aR = mfma16(nh, xih, aR); aR = mfma16(nh, xil, aR); aR = mfma16(nl, xih, aR);
        aI = mfma16(sh, xrh, aI); aI = mfma16(sh, xrl, aI); aI = mfma16(sl, xrh, aI);
        aI = mfma16(ch, xih, aI); aI = mfma16(ch, xil, aI); aI = mfma16(cl, xih, aI);
        #pragma unroll
        for (int r = 0; r < 4; r++) {
            int h = ht * 16 + g * 4 + r;
            float vR = aR[r] * s, vI = aI[r] * s;
            unsigned short hR = f2bf(vR), hI = f2bf(vI);
            unsigned short lR = f2bf(vR - bf2f(hR)), lI = f2bf(vI - bf2f(hI));
            ((unsigned int*)(Zb + h * 64))[lx]      = (unsigned)hR | ((unsigned)hI << 16);
            ((unsigned int*)(Zb + h * 64 + 32))[lx] = (unsigned)lR | ((unsigned)lI << 16);
        }
    }
}

// ---------------- layer tail: TRANSPOSED MFMA (D[w][co]) + Ti software pipeline ----------------
// __launch_bounds__(256,4): force total regs <=128/thread so 4 waves/SIMD fit (LDS allows 4 blocks/CU).
__global__ __launch_bounds__(256, 4) void k_tail(unsigned short* __restrict__ X, const unsigned short* __restrict__ Zs,
                                              const unsigned short* __restrict__ WH, const unsigned short* __restrict__ WL,
                                              const float* __restrict__ sbl, const float* __restrict__ bng,
                                              const float* __restrict__ bnb, const float* __restrict__ bnm,
                                              const float* __restrict__ bnv,
                                              const unsigned short* __restrict__ TiH, const unsigned short* __restrict__ TiL,
                                              const unsigned short* __restrict__ TfH, const unsigned short* __restrict__ TfL,
                                              float2* __restrict__ Y, int mode,
                                              const unsigned short* __restrict__ PH, const unsigned short* __restrict__ PL,
                                              const float* __restrict__ pb, float* __restrict__ ACC) {
    __shared__ unsigned short xl[64 * 264];   // 33,792 B
    __shared__ float cbs[64];
    __shared__ float pacc[64];
    __shared__ float pbs[64];
    int b = blockIdx.x >> 8, h = blockIdx.x & 255;
    int t = threadIdx.x;
    unsigned short* Xg = X + (size_t)(b * 256 + h) * 16384;
    // contiguous 32KB staging: 16B per lane
    #pragma unroll
    for (int r = 0; r < 8; r++) {
        int idx = r * 256 + t;
        int c = idx >> 5, w8 = idx & 31;
        *(short8*)(&xl[c * 264 + w8 * 8]) = *(const short8*)(Xg + idx * 8);
    }
    if (t < 64) {
        float scl = bng[t] * rsqrtf(bnv[t] + 1e-5f);
        cbs[t] = scl * (sbl[t] - bnm[t]) + bnb[t];
        pacc[t] = 0.f;
        pbs[t] = pb[t];
    }
    __syncthreads();

    int wv = t >> 6, ln = t & 63;
    int lx = ln & 15, q = ln >> 4;

    // ---- Az fragments: pure b128 loads (pre-scaled, pre-split by k_inv_h) ----
    short8 azh[4], azl[4];
    {
        const unsigned short* Zg = Zs + (size_t)(b * 64) * 16384 + h * 64;
        #pragma unroll
        for (int mt = 0; mt < 4; mt++) {
            const unsigned short* zp = Zg + (size_t)(mt * 16 + lx) * 16384 + q * 8;
            azh[mt] = *(const short8*)(zp);
            azl[mt] = *(const short8*)(zp + 32);
        }
    }

    // ---- per-nt strips with Ti software pipeline ----
    short8 tah = *(const short8*)(TiH + (wv * 64 + lx) * 32 + q * 8);
    short8 tal = *(const short8*)(TiL + (wv * 64 + lx) * 32 + q * 8);
    #pragma unroll 1
    for (int nt = 0; nt < 4; nt++) {
        int w0 = wv * 64 + nt * 16;
        int w = w0 + lx;
        short8 tah_c = tah, tal_c = tal;
        if (nt < 3) {   // issue next strip's table loads early; latency hides under MFMA/epilogue
            tah = *(const short8*)(TiH + (w + 16) * 32 + q * 8);
            tal = *(const short8*)(TiL + (w + 16) * 32 + q * 8);
        }
        f32x4 acc[4];
        #pragma unroll
        for (int mt = 0; mt < 4; mt++) acc[mt] = (f32x4){0.f, 0.f, 0.f, 0.f};
        // spectral recon: D[w][co] = sum_k Ti[w][k] * Az[k][co]
        #pragma unroll
        for (int mt = 0; mt < 4; mt++) {
            acc[mt] = mfma16(tah_c, azh[mt], acc[mt]);
            acc[mt] = mfma16(tah_c, azl[mt], acc[mt]);
            acc[mt] = mfma16(tal_c, azh[mt], acc[mt]);
        }
        // skip conv: D[w][co] += sum_c x[c][w] * W[co][c]
        #pragma unroll
        for (int ks = 0; ks < 2; ks++) {
            int k0 = ks * 32;
            short8 afr;
            #pragma unroll
            for (int j = 0; j < 8; j++)
                afr[j] = (short)xl[(k0 + q * 8 + j) * 264 + w];
            #pragma unroll
            for (int mt = 0; mt < 4; mt++) {
                short8 bh = *(const short8*)(WH + (mt * 16 + lx) * 64 + k0 + q * 8);
                short8 bl = *(const short8*)(WL + (mt * 16 + lx) * 64 + k0 + q * 8);
                acc[mt] = mfma16(afr, bh, acc[mt]);
                acc[mt] = mfma16(afr, bl, acc[mt]);
            }
        }
        // epilogue: xnew = gelu(D + cb) + xold, b64 vectorized (4 consecutive w per lane)
        #pragma unroll
        for (int mt = 0; mt < 4; mt++) {
            int co = mt * 16 + lx;
            float cb = cbs[co];
            unsigned short* xp = &xl[co * 264 + w0 + q * 4];
            short4v old = *(const short4v*)xp;
            short4v nw;
            #pragma unroll
            for (int r = 0; r < 4; r++) {
                float y = acc[mt][r] + cb;
                float v = gelu_f(y) + bf2f((unsigned short)old[r]);
                nw[r] = (short)f2bf(v);
            }
            *(short4v*)xp = nw;
        }
    }
    __syncthreads();

    if (mode == 1) {
        // fused forward w-DFT for next layer
        f32x4 fa0 = {0.f, 0.f, 0.f, 0.f}, fa1 = {0.f, 0.f, 0.f, 0.f};
        for (int ks = 0; ks < 8; ks++) {
            int k0 = ks * 32;
            short8 a = *(const short8*)(&xl[(wv * 16 + lx) * 264 + k0 + q * 8]);
            short8 bh0 = *(const short8*)(TfH + lx * 256 + k0 + q * 8);
            short8 bl0 = *(const short8*)(TfL + lx * 256 + k0 + q * 8);
            short8 bh1 = *(const short8*)(TfH + (16 + lx) * 256 + k0 + q * 8);
            short8 bl1 = *(const short8*)(TfL + (16 + lx) * 256 + k0 + q * 8);
            fa0 = mfma16(a, bh0, fa0); fa0 = mfma16(a, bl0, fa0);
            fa1 = mfma16(a, bh1, fa1); fa1 = mfma16(a, bl1, fa1);
        }
        #pragma unroll
        for (int r = 0; r < 4; r++) {
            int c = wv * 16 + q * 4 + r;
            Y[(b * 64 + c) * 4096 + h * 16 + lx] = make_float2(fa0[r], fa1[r]);
        }
        // contiguous X writeback
        #pragma unroll
        for (int r = 0; r < 8; r++) {
            int idx = r * 256 + t;
            int c = idx >> 5, w8 = idx & 31;
            *(short8*)(Xg + idx * 8) = *(const short8*)(&xl[c * 264 + w8 * 8]);
        }
    } else {
        // fused proj conv + GELU + spatial sum (reads NEW xl), transposed
        float psum[4][4];
        #pragma unroll
        for (int mt = 0; mt < 4; mt++)
            #pragma unroll
            for (int r = 0; r < 4; r++) psum[mt][r] = 0.f;
        #pragma unroll 1
        for (int nt = 0; nt < 4; nt++) {
            int w = wv * 64 + nt * 16 + lx;
            f32x4 acc[4];
            #pragma unroll
            for (int mt = 0; mt < 4; mt++) acc[mt] = (f32x4){0.f, 0.f, 0.f, 0.f};
            #pragma unroll
            for (int ks = 0; ks < 2; ks++) {
                int k0 = ks * 32;
                short8 afr;
                #pragma unroll
                for (int j = 0; j < 8; j++)
                    afr[j] = (short)xl[(k0 + q * 8 + j) * 264 + w];
                #pragma unroll
                for (int mt = 0; mt < 4; mt++) {
                    short8 bh = *(const short8*)(PH + (mt * 16 + lx) * 64 + k0 + q * 8);
                    short8 bl = *(const short8*)(PL + (mt * 16 + lx) * 64 + k0 + q * 8);
                    acc[mt] = mfma16(afr, bh, acc[mt]);
                    acc[mt] = mfma16(afr, bl, acc[mt]);
                }
            }
            #pragma unroll
            for (int mt = 0; mt < 4; mt++) {
                int co = mt * 16 + lx;
                #pragma unroll
                for (int r = 0; r < 4; r++)
                    psum[mt][r] += gelu_f(acc[mt][r] + pbs[co]);
            }
        }
        #pragma unroll
        for (int mt = 0; mt < 4; mt++) {
            int co = mt * 16 + lx;
            float s = psum[mt][0] + psum[mt][1] + psum[mt][2] + psum[mt][3];
            s += __shfl_xor(s, 16, 64);
            s += __shfl_xor(s, 32, 64);
            if (q == 0) atomicAdd(&pacc[co], s);
        }
        __syncthreads();
        if (t < 64) atomicAdd(&ACC[b * 64 + t], pacc[t]);
    }
}

// ---------------- heads ----------------
__global__ __launch_bounds__(128) void k_head(const float* __restrict__ ACC, const float* __restrict__ env,
                                              const float* __restrict__ d1d,
                                              const float* __restrict__ dw1, const float* __restrict__ db1,
                                              const float* __restrict__ dw2, const float* __restrict__ db2,
                                              const float* __restrict__ dw3, const float* __restrict__ db3,
                                              const float* __restrict__ iw1, const float* __restrict__ ib1,
                                              const float* __restrict__ iw2, const float* __restrict__ ib2,
                                              const float* __restrict__ iw3, const float* __restrict__ ib3,
                                              float* __restrict__ out) {
    __shared__ float xc[108];
    __shared__ float h1[128];
    __shared__ float h2[64];
    int b = blockIdx.x, t = threadIdx.x;
    if (t < 64) xc[t] = ACC[b * 64 + t] * (1.0f / 65536.0f);
    else if (t < 104) xc[t] = env[b * 40 + (t - 64)];
    else if (t < 108) xc[t] = d1d[b * 4 + (t - 104)];
    __syncthreads();
    {
        float a = db1[t];
        for (int k = 0; k < 108; k++) a += xc[k] * dw1[t * 108 + k];
        h1[t] = gelu_f(a);
    }
    __syncthreads();
    if (t < 64) {
        float a = db2[t];
        for (int k = 0; k < 128; k++) a += h1[k] * dw2[t * 128 + k];
        h2[t] = gelu_f(a);
    }
    __syncthreads();
    if (t < 8) {
        float a = db3[t];
        for (int k = 0; k < 64; k++) a += h2[k] * dw3[t * 64 + k];
        out[b * 8 + t] = a;
    }
    __syncthreads();
    {
        float a = ib1[t];
        for (int k = 0; k < 108; k++) a += xc[k] * iw1[t * 108 + k];
        h1[t] = gelu_f(a);
    }
    __syncthreads();
    if (t < 64) {
        float a = ib2[t];
        for (int k = 0; k < 128; k++) a += h1[k] * iw2[t * 128 + k];
        h2[t] = gelu_f(a);
    }
    __syncthreads();
    if (t < 4) {
        float a = ib3[t];
        for (int k = 0; k < 64; k++) a += h2[k] * iw3[t * 64 + k];
        out[128 + b * 4 + t] = a;
    }
}

extern "C" void kernel_launch(void* const* d_in, const int* in_sizes, int n_in,
                              void* d_out, int out_size, void* d_ws, size_t ws_size,
                              hipStream_t stream) {
    const float* grid_  = (const float*)d_in[0];
    const float* env    = (const float*)d_in[1];
    const float* d1d    = (const float*)d_in[2];
    const float* lift_w = (const float*)d_in[3];
    const float* lift_b = (const float*)d_in[4];
    const float* w1r    = (const float*)d_in[5];
    const float* w1i    = (const float*)d_in[6];
    const float* w2r    = (const float*)d_in[7];
    const float* w2i    = (const float*)d_in[8];
    const float* skip_w = (const float*)d_in[9];
    const float* skip_b = (const float*)d_in[10];
    const float* bn_g   = (const float*)d_in[11];
    const float* bn_b   = (const float*)d_in[12];
    const float* bn_m   = (const float*)d_in[13];
    const float* bn_v   = (const float*)d_in[14];
    const float* proj_w = (const float*)d_in[15];
    const float* proj_b = (const float*)d_in[16];
    const float* dw1 = (const float*)d_in[17];
    const float* db1 = (const float*)d_in[18];
    const float* dw2 = (const float*)d_in[19];
    const float* db2 = (const float*)d_in[20];
    const float* dw3 = (const float*)d_in[21];
    const float* db3 = (const float*)d_in[22];
    const float* iw1 = (const float*)d_in[23];
    const float* ib1 = (const float*)d_in[24];
    const float* iw2 = (const float*)d_in[25];
    const float* ib2 = (const float*)d_in[26];
    const float* iw3 = (const float*)d_in[27];
    const float* ib3 = (const float*)d_in[28];

    // Workspace layout (total ~193.3 MB)
    char* ws = (char*)d_ws;
    unsigned short* X   = (unsigned short*)(ws);               // 134,217,728  [b][h][c][w]
    float2* S   = (float2*)(ws + 134217728);                   //  33,554,432 (Y and Z alias; Z = bf16 hi/lo planes)
    float2* XF  = (float2*)(ws + 167772160);                   //   4,194,304
    float2* YF  = (float2*)(ws + 171966464);                   //   4,194,304
    float2* WPK = (float2*)(ws + 176160768);                   //  16,777,216
    float*  ACC = (float*)(ws + 192937984);                    //       4,096
    unsigned short* TfH = (unsigned short*)(ws + 192942080);   //      16,384
    unsigned short* TfL = (unsigned short*)(ws + 192958464);   //      16,384
    unsigned short* TiH = (unsigned short*)(ws + 192974848);   //      16,384
    unsigned short* TiL = (unsigned short*)(ws + 192991232);   //      16,384
    unsigned short* WH  = (unsigned short*)(ws + 193007616);   //      32,768
    unsigned short* WL  = (unsigned short*)(ws + 193040384);   //      32,768
    unsigned short* PH  = (unsigned short*)(ws + 193073152);   //       8,192
    unsigned short* PL  = (unsigned short*)(ws + 193081344);   //       8,192
    // h-DFT MFMA tables (12 x 16,384 B)
    unsigned short* FcH = (unsigned short*)(ws + 193089536);
    unsigned short* FcL = (unsigned short*)(ws + 193105920);
    unsigned short* FsH = (unsigned short*)(ws + 193122304);
    unsigned short* FsL = (unsigned short*)(ws + 193138688);
    unsigned short* FnH = (unsigned short*)(ws + 193155072);
    unsigned short* FnL = (unsigned short*)(ws + 193171456);
    unsigned short* IcH = (unsigned short*)(ws + 193187840);
    unsigned short* IcL = (unsigned short*)(ws + 193204224);
    unsigned short* IsH = (unsigned short*)(ws + 193220608);
    unsigned short* IsL = (unsigned short*)(ws + 193236992);
    unsigned short* InH = (unsigned short*)(ws + 193253376);
    unsigned short* InL = (unsigned short*)(ws + 193269760);
    // lift weights bf16 hi/lo [64][32] (2 x 4,096 B)
    unsigned short* LwH = (unsigned short*)(ws + 193286144);
    unsigned short* LwL = (unsigned short*)(ws + 193290240);   // end 193,294,336

    unsigned short* Zs = (unsigned short*)S;   // Z bf16 hi/lo view (byte-coincident with Y rows)

    hipMemsetAsync(ACC, 0, 1024 * sizeof(float), stream);
    k_prep<<<216, 256, 0, stream>>>(skip_w, bn_g, bn_v, proj_w, lift_w,
                                    TfH, TfL, TiH, TiL, WH, WL, PH, PL,
                                    FcH, FcL, FsH, FsL, FnH, FnL, IcH, IcL, IsH, IsL, InH, InL,
                                    LwH, LwL);
    k_lift<<<8192, 256, 0, stream>>>(grid_, LwH, LwL, lift_b, X, TfH, TfL, S);
    for (int l = 0; l < L_; l++) {
        k_fwd_h<<<1024, 256, 0, stream>>>(S, XF, FcH, FcL, FsH, FsL, FnH, FnL,
                                          w1r, w1i, w2r, w2i, WPK, l);
        k_mix<<<512, 256, 0, stream>>>(XF, WPK, YF);
        k_inv_h<<<1024, 256, 0, stream>>>(YF, Zs, IcH, IcL, IsH, IsL, InH, InL,
                                          bn_g + l * 64, bn_v + l * 64);
        k_tail<<<4096, 256, 0, stream>>>(X, Zs, WH + l * 4096, WL + l * 4096,
                                         skip_b + l * 64, bn_g + l * 64, bn_b + l * 64,
                                         bn_m + l * 64, bn_v + l * 64,
                                         TiH, TiL, TfH, TfL, S, (l < 3) ? 1 : 2,
                                         PH, PL, proj_b, ACC);
    }
    k_head<<<16, 128, 0, stream>>>(ACC, env, d1d, dw1, db1, dw2, db2, dw3, db3,
                                   iw1, ib1, iw2, ib2, iw3, ib3, (float*)d_out);
}

// Round 10
// 1108.822 us; speedup vs baseline: 1.2380x; 1.2380x over previous
//
#include <hip/hip_runtime.h>
#include <hip/hip_bf16.h>
#include <math.h>

#define B_ 16
#define CIN_ 15
#define C_ 64
#define L_ 4

typedef __attribute__((ext_vector_type(8))) short short8;
typedef __attribute__((ext_vector_type(4))) short short4v;
typedef __attribute__((ext_vector_type(4))) float f32x4;

// Fast exact-GELU: erf via Abramowitz-Stegun 7.1.26 (|eps| <= 1.5e-7), branchless.
__device__ __forceinline__ float gelu_f(float x) {
    float z = fabsf(x) * 0.70710678118654752440f;
    float t = __builtin_amdgcn_rcpf(fmaf(0.3275911f, z, 1.0f));
    float p = t * fmaf(t, fmaf(t, fmaf(t, fmaf(t, 1.061405429f, -1.453152027f), 1.421413741f), -0.284496736f), 0.254829592f);
    float e = __expf(-z * z);
    float E = fmaf(-p, e, 1.0f);
    return 0.5f * fmaf(fabsf(x), E, x);
}

__device__ __forceinline__ unsigned short f2bf(float x) {
    __hip_bfloat16 h = __float2bfloat16(x);
    return *(unsigned short*)&h;
}
__device__ __forceinline__ float bf2f(unsigned short u) {
    __hip_bfloat16 h = *(__hip_bfloat16*)&u;
    return __bfloat162float(h);
}
__device__ __forceinline__ f32x4 mfma16(short8 a, short8 b, f32x4 c) {
    return __builtin_amdgcn_mfma_f32_16x16x32_bf16(a, b, c, 0, 0, 0);
}

#define TWO_PI_OVER_256 0.024543692606170259674f

// ---------------- one-time prep: split tables & weights into bf16 hi/lo ----------------
__global__ __launch_bounds__(256) void k_prep(const float* __restrict__ skip_w,
                                              const float* __restrict__ bn_g, const float* __restrict__ bn_v,
                                              const float* __restrict__ proj_w, const float* __restrict__ lift_w,
                                              unsigned short* __restrict__ TfH, unsigned short* __restrict__ TfL,
                                              unsigned short* __restrict__ TiH, unsigned short* __restrict__ TiL,
                                              unsigned short* __restrict__ WH, unsigned short* __restrict__ WL,
                                              unsigned short* __restrict__ PH, unsigned short* __restrict__ PL,
                                              unsigned short* __restrict__ FcH, unsigned short* __restrict__ FcL,
                                              unsigned short* __restrict__ FsH, unsigned short* __restrict__ FsL,
                                              unsigned short* __restrict__ FnH, unsigned short* __restrict__ FnL,
                                              unsigned short* __restrict__ IcH, unsigned short* __restrict__ IcL,
                                              unsigned short* __restrict__ IsH, unsigned short* __restrict__ IsL,
                                              unsigned short* __restrict__ InH, unsigned short* __restrict__ InL,
                                              unsigned short* __restrict__ LwH, unsigned short* __restrict__ LwL) {
    int id = blockIdx.x * 256 + threadIdx.x;
    if (id < 8192) {
        int col = id >> 8, w = id & 255;
        int kk = (col < 16) ? col : (col - 16);
        float s, c;
        sincosf(TWO_PI_OVER_256 * (float)((w * kk) & 255), &s, &c);
        float v = (col < 16) ? c : -s;
        unsigned short hi = f2bf(v);
        TfH[id] = hi; TfL[id] = f2bf(v - bf2f(hi));
    } else if (id < 16384) {
        int idx = id - 8192;
        int w = idx >> 5, k = idx & 31, ky = k >> 1;
        float s, c;
        sincosf(TWO_PI_OVER_256 * (float)((w * ky) & 255), &s, &c);
        float v = (k & 1) ? -s : c;
        unsigned short hi = f2bf(v);
        TiH[idx] = hi; TiL[idx] = f2bf(v - bf2f(hi));
    } else if (id < 32768) {
        int idx = id - 16384;
        int lco = idx >> 6;
        float scl = bn_g[lco] * rsqrtf(bn_v[lco] + 1e-5f);
        float v = scl * skip_w[idx];
        unsigned short hi = f2bf(v);
        WH[idx] = hi; WL[idx] = f2bf(v - bf2f(hi));
    } else if (id < 36864) {
        int idx = id - 32768;
        float v = proj_w[idx];
        unsigned short hi = f2bf(v);
        PH[idx] = hi; PL[idx] = f2bf(v - bf2f(hi));
    } else if (id < 45056) {
        int idx = id - 36864;          // fwd tables [j=32][h=256]
        int j = idx >> 8, h = idx & 255;
        int kxu = j + ((j < 16) ? 0 : 224);
        float s, c;
        sincosf(TWO_PI_OVER_256 * (float)((h * kxu) & 255), &s, &c);
        unsigned short ch = f2bf(c);
        FcH[idx] = ch; FcL[idx] = f2bf(c - bf2f(ch));
        unsigned short sh = f2bf(s);
        unsigned short sl = f2bf(s - bf2f(sh));
        FsH[idx] = sh; FsL[idx] = sl;
        FnH[idx] = sh ^ 0x8000; FnL[idx] = sl ^ 0x8000;   // exact negation in bf16
    } else if (id < 53248) {
        int idx = id - 45056;          // inv tables [h=256][j=32]
        int h = idx >> 5, j = idx & 31;
        int kxu = j + ((j < 16) ? 0 : 224);
        float s, c;
        sincosf(TWO_PI_OVER_256 * (float)((h * kxu) & 255), &s, &c);
        unsigned short ch = f2bf(c);
        IcH[idx] = ch; IcL[idx] = f2bf(c - bf2f(ch));
        unsigned short sh = f2bf(s);
        unsigned short sl = f2bf(s - bf2f(sh));
        IsH[idx] = sh; IsL[idx] = sl;
        InH[idx] = sh ^ 0x8000; InL[idx] = sl ^ 0x8000;
    } else if (id < 55296) {
        int idx = id - 53248;          // lift weights [co=64][k=32] (k>=15 zero-padded)
        int co = idx >> 5, k = idx & 31;
        float v = (k < CIN_) ? lift_w[co * CIN_ + k] : 0.0f;
        unsigned short hi = f2bf(v);
        LwH[idx] = hi; LwL[idx] = f2bf(v - bf2f(hi));
    }
}

// ---------------- lift conv1x1 (15->64) via MFMA + GELU + fused forward w-DFT ----------------
// C-SPLIT for occupancy: 8192 blocks, each (b, h, c-half of 32). LDS ~17KB -> 8 blocks/CU.
// X layout [b][h][c][w]: each block writes a contiguous 16KB half-stream.
__global__ __launch_bounds__(256) void k_lift(const float* __restrict__ g,
                                              const unsigned short* __restrict__ LwH, const unsigned short* __restrict__ LwL,
                                              const float* __restrict__ lb, unsigned short* __restrict__ X,
                                              const unsigned short* __restrict__ TfH, const unsigned short* __restrict__ TfL,
                                              float2* __restrict__ Y) {
    __shared__ unsigned short xl[32 * 264];
    __shared__ float lbs[C_];
    int b = blockIdx.x >> 9, h = (blockIdx.x >> 1) & 255, ch = blockIdx.x & 1;
    int t = threadIdx.x;
    if (t < C_) lbs[t] = lb[t];
    int wv = t >> 6, ln = t & 63;
    int lx = ln & 15, q = ln >> 4;
    int cob = ch * 32;
    // B-frags: col co = cob + mt*16+lx, k = q*8+j
    short8 bwh[2], bwl[2];
    #pragma unroll
    for (int mt = 0; mt < 2; mt++) {
        bwh[mt] = *(const short8*)(LwH + (cob + mt * 16 + lx) * 32 + q * 8);
        bwl[mt] = *(const short8*)(LwL + (cob + mt * 16 + lx) * 32 + q * 8);
    }
    __syncthreads();
    const float* gb = g + ((size_t)(b * CIN_) * 256 + h) * 256;  // + ci*65536 + w
    #pragma unroll 1
    for (int nt = 0; nt < 4; nt++) {
        int w0 = wv * 64 + nt * 16;
        int w = w0 + lx;
        // A-frag: row = w (lane lx), k = ci = q*8+j  (zero for ci >= 15)
        short8 agh = {0, 0, 0, 0, 0, 0, 0, 0};
        short8 agl = {0, 0, 0, 0, 0, 0, 0, 0};
        #pragma unroll
        for (int j = 0; j < 8; j++) {
            int ci = q * 8 + j;
            if (ci < CIN_) {
                float v = gb[(size_t)ci * 65536 + w];
                unsigned short hv = f2bf(v);
                agh[j] = (short)hv;
                agl[j] = (short)f2bf(v - bf2f(hv));
            }
        }
        f32x4 acc[2];
        #pragma unroll
        for (int mt = 0; mt < 2; mt++) acc[mt] = (f32x4){0.f, 0.f, 0.f, 0.f};
        #pragma unroll
        for (int mt = 0; mt < 2; mt++) {
            acc[mt] = mfma16(agh, bwh[mt], acc[mt]);
            acc[mt] = mfma16(agh, bwl[mt], acc[mt]);
            acc[mt] = mfma16(agl, bwh[mt], acc[mt]);
        }
        // epilogue: xl = gelu(D + bias), b64 vectorized (lane holds w = w0+q*4+r, c_local = mt*16+lx)
        #pragma unroll
        for (int mt = 0; mt < 2; mt++) {
            int cl = mt * 16 + lx;
            float bias = lbs[cob + cl];
            short4v nw;
            #pragma unroll
            for (int r = 0; r < 4; r++)
                nw[r] = (short)f2bf(gelu_f(acc[mt][r] + bias));
            *(short4v*)(&xl[cl * 264 + w0 + q * 4]) = nw;
        }
    }
    __syncthreads();
    // forward w-DFT: 32 c-rows handled by waves 0,1 (A-row = lane&15 fixes 16 rows/wave)
    if (wv < 2) {
        f32x4 fa0 = {0.f, 0.f, 0.f, 0.f}, fa1 = {0.f, 0.f, 0.f, 0.f};
        for (int ks = 0; ks < 8; ks++) {
            int k0 = ks * 32;
            short8 a = *(const short8*)(&xl[(wv * 16 + lx) * 264 + k0 + q * 8]);
            short8 bh0 = *(const short8*)(TfH + lx * 256 + k0 + q * 8);
            short8 bl0 = *(const short8*)(TfL + lx * 256 + k0 + q * 8);
            short8 bh1 = *(const short8*)(TfH + (16 + lx) * 256 + k0 + q * 8);
            short8 bl1 = *(const short8*)(TfL + (16 + lx) * 256 + k0 + q * 8);
            fa0 = mfma16(a, bh0, fa0); fa0 = mfma16(a, bl0, fa0);
            fa1 = mfma16(a, bh1, fa1); fa1 = mfma16(a, bl1, fa1);
        }
        #pragma unroll
        for (int r = 0; r < 4; r++) {
            int c = cob + wv * 16 + q * 4 + r;
            Y[(b * 64 + c) * 4096 + h * 16 + lx] = make_float2(fa0[r], fa1[r]);
        }
    }
    // contiguous 16KB X half-write: X[b][h][c][w]
    unsigned short* Xg = X + (size_t)(b * 256 + h) * 16384 + ch * 8192;
    #pragma unroll
    for (int r = 0; r < 4; r++) {
        int idx = r * 256 + t;
        int c = idx >> 5, w8 = idx & 31;
        *(short8*)(Xg + idx * 8) = *(const short8*)(&xl[c * 264 + w8 * 8]);
    }
}

// ---------------- forward partial DFT over h — MFMA version + FUSED weight repack ----------------
// Repack for this layer rides in the latency shadow: block bc also moves (j=bc>>5, i=(bc&31)*2 +{0,1})
// of WPK. k_mix (launched after on the same stream) is the only WPK consumer -> ordering safe.
__global__ __launch_bounds__(256) void k_fwd_h(const float2* __restrict__ Y, float2* __restrict__ XF,
                                               const unsigned short* __restrict__ FcH, const unsigned short* __restrict__ FcL,
                                               const unsigned short* __restrict__ FsH, const unsigned short* __restrict__ FsL,
                                               const unsigned short* __restrict__ FnH, const unsigned short* __restrict__ FnL,
                                               const float* __restrict__ w1r, const float* __restrict__ w1i,
                                               const float* __restrict__ w2r, const float* __restrict__ w2i,
                                               float2* __restrict__ WPK, int l) {
    __shared__ float red[4][2][2][64][4];   // [wave][rowtile][R/I][lane][reg] = 16 KB
    int bc = blockIdx.x;
    int t = threadIdx.x;
    int wv = t >> 6, lid = t & 63, lx = lid & 15, g = lid >> 4;
    const float2* Yb = Y + (size_t)bc * 4096;
    f32x4 aR[2], aI[2];
    aR[0] = (f32x4){0.f,0.f,0.f,0.f}; aR[1] = aR[0]; aI[0] = aR[0]; aI[1] = aR[0];
    #pragma unroll
    for (int kk = 0; kk < 2; kk++) {
        int ks = wv * 2 + kk;
        short8 yrh, yrl, yih, yil;
        #pragma unroll
        for (int j = 0; j < 8; j++) {
            float2 v = Yb[(ks * 32 + g * 8 + j) * 16 + lx];
            unsigned short h1 = f2bf(v.x);
            yrh[j] = (short)h1; yrl[j] = (short)f2bf(v.x - bf2f(h1));
            unsigned short h2 = f2bf(v.y);
            yih[j] = (short)h2; yil[j] = (short)f2bf(v.y - bf2f(h2));
        }
        #pragma unroll
        for (int rt = 0; rt < 2; rt++) {
            int base = (rt * 16 + lx) * 256 + ks * 32 + g * 8;
            short8 ch = *(const short8*)(FcH + base);
            short8 cl = *(const short8*)(FcL + base);
            short8 sh = *(const short8*)(FsH + base);
            short8 sl = *(const short8*)(FsL + base);
            short8 nh = *(const short8*)(FnH + base);
            short8 nl = *(const short8*)(FnL + base);
            // re = cos.Yr + sin.Yi ; im = cos.Yi - sin.Yr
            aR[rt] = mfma16(ch, yrh, aR[rt]);
            aR[rt] = mfma16(ch, yrl, aR[rt]);
            aR[rt] = mfma16(cl, yrh, aR[rt]);
            aR[rt] = mfma16(sh, yih, aR[rt]);
            aR[rt] = mfma16(sh, yil, aR[rt]);
            aR[rt] = mfma16(sl, yih, aR[rt]);
            aI[rt] = mfma16(ch, yih, aI[rt]);
            aI[rt] = mfma16(ch, yil, aI[rt]);
            aI[rt] = mfma16(cl, yih, aI[rt]);
            aI[rt] = mfma16(nh, yrh, aI[rt]);
            aI[rt] = mfma16(nh, yrl, aI[rt]);
            aI[rt] = mfma16(nl, yrh, aI[rt]);
        }
    }
    #pragma unroll
    for (int rt = 0; rt < 2; rt++) {
        *(f32x4*)&red[wv][rt][0][lid][0] = aR[rt];
        *(f32x4*)&red[wv][rt][1][lid][0] = aI[rt];
    }
    // ---- fused repack (independent; loads overlap the barrier wait) ----
    {
        int j = bc >> 5;            // 0..31
        int i2 = (bc & 31) * 2;     // 0,2,...,62
        int ky = t & 15, o0 = (t >> 4) * 4;
        int x = j & 15;
        const float* wr = (j < 16) ? w1r : w2r;
        const float* wi = (j < 16) ? w1i : w2i;
        #pragma unroll
        for (int ii = 0; ii < 2; ii++) {
            int i = i2 + ii;
            size_t sb = ((size_t)(l * 64 + i) * 64 + o0) * 256 + x * 16 + ky;
            float r0 = wr[sb];       float v0 = wi[sb];
            float r1 = wr[sb + 256]; float v1 = wi[sb + 256];
            float r2 = wr[sb + 512]; float v2 = wi[sb + 512];
            float r3 = wr[sb + 768]; float v3 = wi[sb + 768];
            float4* dst = (float4*)(WPK + ((size_t)(j * 16 + ky) * 64 + i) * 64 + o0);
            dst[0] = make_float4(r0, v0, r1, v1);
            dst[1] = make_float4(r2, v2, r3, v3);
        }
    }
    __syncthreads();
    if (t < 128) {
        int rt = t >> 6, ll = t & 63;
        int llx = ll & 15, gg = ll >> 4;
        f32x4 R = *(const f32x4*)&red[0][rt][0][ll][0];
        f32x4 I = *(const f32x4*)&red[0][rt][1][ll][0];
        #pragma unroll
        for (int w = 1; w < 4; w++) {
            R += *(const f32x4*)&red[w][rt][0][ll][0];
            I += *(const f32x4*)&red[w][rt][1][ll][0];
        }
        #pragma unroll
        for (int r = 0; r < 4; r++) {
            int j = rt * 16 + gg * 4 + r;
            XF[(j * 16 + llx) * 1024 + bc] = make_float2(R[r], I[r]);
        }
    }
}

// ---------------- mode mix: W tile staged in LDS ----------------
__global__ __launch_bounds__(256) void k_mix(const float2* __restrict__ XF, const float2* __restrict__ WPK,
                                             float2* __restrict__ YF) {
    __shared__ float2 xs[1024];
    __shared__ float2 wls[4096];
    int s = blockIdx.x;
    int t = threadIdx.x;
    for (int idx = t; idx < 1024; idx += 256) xs[idx] = XF[s * 1024 + idx];
    for (int idx = t; idx < 4096; idx += 256) wls[idx] = WPK[(size_t)s * 4096 + idx];
    __syncthreads();
    int o = t & 63, bg = t >> 6;
    float2 acc[4];
    #pragma unroll
    for (int q = 0; q < 4; q++) acc[q] = make_float2(0.f, 0.f);
    for (int i = 0; i < 64; i++) {
        float2 wv = wls[i * 64 + o];
        #pragma unroll
        for (int q = 0; q < 4; q++) {
            float2 xv = xs[(bg * 4 + q) * 64 + i];
            acc[q].x += xv.x * wv.x - xv.y * wv.y;
            acc[q].y += xv.x * wv.y + xv.y * wv.x;
        }
    }
    #pragma unroll
    for (int q = 0; q < 4; q++) {
        int b = bg * 4 + q;
        YF[(b * 64 + o) * 512 + s] = acc[q];
    }
}

// ---------------- inverse DFT over kx — MFMA, emits PRE-SCALED, PRE-SPLIT bf16 hi/lo Z ----------------
__global__ __launch_bounds__(256) void k_inv_h(const float2* __restrict__ YF, unsigned short* __restrict__ Zs,
                                               const unsigned short* __restrict__ IcH, const unsigned short* __restrict__ IcL,
                                               const unsigned short* __restrict__ IsH, const unsigned short* __restrict__ IsL,
                                               const unsigned short* __restrict__ InH, const unsigned short* __restrict__ InL,
                                               const float* __restrict__ bng, const float* __restrict__ bnv) {
    int bc = blockIdx.x;
    int t = threadIdx.x;
    int wv = t >> 6, l = t & 63, lx = l & 15, g = l >> 4;
    const float2* Yb = YF + (size_t)bc * 512;
    short8 xrh, xrl, xih, xil;
    #pragma unroll
    for (int jj = 0; jj < 8; jj++) {
        float2 v = Yb[(g * 8 + jj) * 16 + lx];
        unsigned short h1 = f2bf(v.x);
        xrh[jj] = (short)h1; xrl[jj] = (short)f2bf(v.x - bf2f(h1));
        unsigned short h2 = f2bf(v.y);
        xih[jj] = (short)h2; xil[jj] = (short)f2bf(v.y - bf2f(h2));
    }
    int c = bc & 63;
    float s = bng[c] * rsqrtf(bnv[c] + 1e-5f) * ((lx == 0) ? (1.0f / 65536.0f) : (2.0f / 65536.0f));
    unsigned short* Zb = Zs + (size_t)bc * 16384;
    #pragma unroll
    for (int hh = 0; hh < 4; hh++) {
        int ht = wv * 4 + hh;
        int base = (ht * 16 + lx) * 32 + g * 8;
        short8 ch = *(const short8*)(IcH + base);
        short8 cl = *(const short8*)(IcL + base);
        short8 sh = *(const short8*)(IsH + base);
        short8 sl = *(const short8*)(IsL + base);
        short8 nh = *(const short8*)(InH + base);
        short8 nl = *(const short8*)(InL + base);
        f32x4 aR = {0.f,0.f,0.f,0.f}, aI = {0.f,0.f,0.f,0.f};
        // zr = cos.Xr - sin.Xi ; zi = sin.Xr + cos.Xi
        aR = mfma16(ch, xrh, aR); aR = mfma16(ch, xrl, aR); aR = mfma16(cl, xrh, aR);
        aR = mfma16(nh, xih, aR); aR = mfma16(nh, xil, aR); aR = mfma16(nl, xih, aR);
        aI = mfma16(sh, xrh, aI); aI = mfma16(sh, xrl, aI); aI = mfma16(sl, xrh, aI);
        aI = mfma16(ch, xih, aI); aI = mfma16(ch, xil, aI); aI = mfma16(cl, xih, aI);
        #pragma unroll
        for (int r = 0; r < 4; r++) {
            int h = ht * 16 + g * 4 + r;
            float vR = aR[r] * s, vI = aI[r] * s;
            unsigned short hR = f2bf(vR), hI = f2bf(vI);
            unsigned short lR = f2bf(vR - bf2f(hR)), lI = f2bf(vI - bf2f(hI));
            ((unsigned int*)(Zb + h * 64))[lx]      = (unsigned)hR | ((unsigned)hI << 16);
            ((unsigned int*)(Zb + h * 64 + 32))[lx] = (unsigned)lR | ((unsigned)lI << 16);
        }
    }
}

// ---------------- layer tail: TRANSPOSED MFMA (D[w][co]) + Ti software pipeline ----------------
// X layout [b][h][c][w]; Z arrives pre-scaled/pre-split -> Az build is 8 b128 loads.
// NO launch_bounds min-wave forcing: (256,4) force-capped VGPRs to 64 and spilled 520MB/dispatch (round 9).
__global__ __launch_bounds__(256) void k_tail(unsigned short* __restrict__ X, const unsigned short* __restrict__ Zs,
                                              const unsigned short* __restrict__ WH, const unsigned short* __restrict__ WL,
                                              const float* __restrict__ sbl, const float* __restrict__ bng,
                                              const float* __restrict__ bnb, const float* __restrict__ bnm,
                                              const float* __restrict__ bnv,
                                              const unsigned short* __restrict__ TiH, const unsigned short* __restrict__ TiL,
                                              const unsigned short* __restrict__ TfH, const unsigned short* __restrict__ TfL,
                                              float2* __restrict__ Y, int mode,
                                              const unsigned short* __restrict__ PH, const unsigned short* __restrict__ PL,
                                              const float* __restrict__ pb, float* __restrict__ ACC) {
    __shared__ unsigned short xl[64 * 264];   // 33,792 B
    __shared__ float cbs[64];
    __shared__ float pacc[64];
    __shared__ float pbs[64];
    int b = blockIdx.x >> 8, h = blockIdx.x & 255;
    int t = threadIdx.x;
    unsigned short* Xg = X + (size_t)(b * 256 + h) * 16384;
    // contiguous 32KB staging: 16B per lane
    #pragma unroll
    for (int r = 0; r < 8; r++) {
        int idx = r * 256 + t;
        int c = idx >> 5, w8 = idx & 31;
        *(short8*)(&xl[c * 264 + w8 * 8]) = *(const short8*)(Xg + idx * 8);
    }
    if (t < 64) {
        float scl = bng[t] * rsqrtf(bnv[t] + 1e-5f);
        cbs[t] = scl * (sbl[t] - bnm[t]) + bnb[t];
        pacc[t] = 0.f;
        pbs[t] = pb[t];
    }
    __syncthreads();

    int wv = t >> 6, ln = t & 63;
    int lx = ln & 15, q = ln >> 4;

    // ---- Az fragments: pure b128 loads (pre-scaled, pre-split by k_inv_h) ----
    short8 azh[4], azl[4];
    {
        const unsigned short* Zg = Zs + (size_t)(b * 64) * 16384 + h * 64;
        #pragma unroll
        for (int mt = 0; mt < 4; mt++) {
            const unsigned short* zp = Zg + (size_t)(mt * 16 + lx) * 16384 + q * 8;
            azh[mt] = *(const short8*)(zp);
            azl[mt] = *(const short8*)(zp + 32);
        }
    }

    // ---- per-nt strips with Ti software pipeline ----
    short8 tah = *(const short8*)(TiH + (wv * 64 + lx) * 32 + q * 8);
    short8 tal = *(const short8*)(TiL + (wv * 64 + lx) * 32 + q * 8);
    #pragma unroll 1
    for (int nt = 0; nt < 4; nt++) {
        int w0 = wv * 64 + nt * 16;
        int w = w0 + lx;
        short8 tah_c = tah, tal_c = tal;
        if (nt < 3) {   // issue next strip's table loads early; latency hides under MFMA/epilogue
            tah = *(const short8*)(TiH + (w + 16) * 32 + q * 8);
            tal = *(const short8*)(TiL + (w + 16) * 32 + q * 8);
        }
        f32x4 acc[4];
        #pragma unroll
        for (int mt = 0; mt < 4; mt++) acc[mt] = (f32x4){0.f, 0.f, 0.f, 0.f};
        // spectral recon: D[w][co] = sum_k Ti[w][k] * Az[k][co]
        #pragma unroll
        for (int mt = 0; mt < 4; mt++) {
            acc[mt] = mfma16(tah_c, azh[mt], acc[mt]);
            acc[mt] = mfma16(tah_c, azl[mt], acc[mt]);
            acc[mt] = mfma16(tal_c, azh[mt], acc[mt]);
        }
        // skip conv: D[w][co] += sum_c x[c][w] * W[co][c]
        #pragma unroll
        for (int ks = 0; ks < 2; ks++) {
            int k0 = ks * 32;
            short8 afr;
            #pragma unroll
            for (int j = 0; j < 8; j++)
                afr[j] = (short)xl[(k0 + q * 8 + j) * 264 + w];
            #pragma unroll
            for (int mt = 0; mt < 4; mt++) {
                short8 bh = *(const short8*)(WH + (mt * 16 + lx) * 64 + k0 + q * 8);
                short8 bl = *(const short8*)(WL + (mt * 16 + lx) * 64 + k0 + q * 8);
                acc[mt] = mfma16(afr, bh, acc[mt]);
                acc[mt] = mfma16(afr, bl, acc[mt]);
            }
        }
        // epilogue: xnew = gelu(D + cb) + xold, b64 vectorized (4 consecutive w per lane)
        #pragma unroll
        for (int mt = 0; mt < 4; mt++) {
            int co = mt * 16 + lx;
            float cb = cbs[co];
            unsigned short* xp = &xl[co * 264 + w0 + q * 4];
            short4v old = *(const short4v*)xp;
            short4v nw;
            #pragma unroll
            for (int r = 0; r < 4; r++) {
                float y = acc[mt][r] + cb;
                float v = gelu_f(y) + bf2f((unsigned short)old[r]);
                nw[r] = (short)f2bf(v);
            }
            *(short4v*)xp = nw;
        }
    }
    __syncthreads();

    if (mode == 1) {
        // fused forward w-DFT for next layer
        f32x4 fa0 = {0.f, 0.f, 0.f, 0.f}, fa1 = {0.f, 0.f, 0.f, 0.f};
        for (int ks = 0; ks < 8; ks++) {
            int k0 = ks * 32;
            short8 a = *(const short8*)(&xl[(wv * 16 + lx) * 264 + k0 + q * 8]);
            short8 bh0 = *(const short8*)(TfH + lx * 256 + k0 + q * 8);
            short8 bl0 = *(const short8*)(TfL + lx * 256 + k0 + q * 8);
            short8 bh1 = *(const short8*)(TfH + (16 + lx) * 256 + k0 + q * 8);
            short8 bl1 = *(const short8*)(TfL + (16 + lx) * 256 + k0 + q * 8);
            fa0 = mfma16(a, bh0, fa0); fa0 = mfma16(a, bl0, fa0);
            fa1 = mfma16(a, bh1, fa1); fa1 = mfma16(a, bl1, fa1);
        }
        #pragma unroll
        for (int r = 0; r < 4; r++) {
            int c = wv * 16 + q * 4 + r;
            Y[(b * 64 + c) * 4096 + h * 16 + lx] = make_float2(fa0[r], fa1[r]);
        }
        // contiguous X writeback
        #pragma unroll
        for (int r = 0; r < 8; r++) {
            int idx = r * 256 + t;
            int c = idx >> 5, w8 = idx & 31;
            *(short8*)(Xg + idx * 8) = *(const short8*)(&xl[c * 264 + w8 * 8]);
        }
    } else {
        // fused proj conv + GELU + spatial sum (reads NEW xl), transposed
        float psum[4][4];
        #pragma unroll
        for (int mt = 0; mt < 4; mt++)
            #pragma unroll
            for (int r = 0; r < 4; r++) psum[mt][r] = 0.f;
        #pragma unroll 1
        for (int nt = 0; nt < 4; nt++) {
            int w = wv * 64 + nt * 16 + lx;
            f32x4 acc[4];
            #pragma unroll
            for (int mt = 0; mt < 4; mt++) acc[mt] = (f32x4){0.f, 0.f, 0.f, 0.f};
            #pragma unroll
            for (int ks = 0; ks < 2; ks++) {
                int k0 = ks * 32;
                short8 afr;
                #pragma unroll
                for (int j = 0; j < 8; j++)
                    afr[j] = (short)xl[(k0 + q * 8 + j) * 264 + w];
                #pragma unroll
                for (int mt = 0; mt < 4; mt++) {
                    short8 bh = *(const short8*)(PH + (mt * 16 + lx) * 64 + k0 + q * 8);
                    short8 bl = *(const short8*)(PL + (mt * 16 + lx) * 64 + k0 + q * 8);
                    acc[mt] = mfma16(afr, bh, acc[mt]);
                    acc[mt] = mfma16(afr, bl, acc[mt]);
                }
            }
            #pragma unroll
            for (int mt = 0; mt < 4; mt++) {
                int co = mt * 16 + lx;
                #pragma unroll
                for (int r = 0; r < 4; r++)
                    psum[mt][r] += gelu_f(acc[mt][r] + pbs[co]);
            }
        }
        #pragma unroll
        for (int mt = 0; mt < 4; mt++) {
            int co = mt * 16 + lx;
            float s = psum[mt][0] + psum[mt][1] + psum[mt][2] + psum[mt][3];
            s += __shfl_xor(s, 16, 64);
            s += __shfl_xor(s, 32, 64);
            if (q == 0) atomicAdd(&pacc[co], s);
        }
        __syncthreads();
        if (t < 64) atomicAdd(&ACC[b * 64 + t], pacc[t]);
    }
}

// ---------------- heads ----------------
__global__ __launch_bounds__(128) void k_head(const float* __restrict__ ACC, const float* __restrict__ env,
                                              const float* __restrict__ d1d,
                                              const float* __restrict__ dw1, const float* __restrict__ db1,
                                              const float* __restrict__ dw2, const float* __restrict__ db2,
                                              const float* __restrict__ dw3, const float* __restrict__ db3,
                                              const float* __restrict__ iw1, const float* __restrict__ ib1,
                                              const float* __restrict__ iw2, const float* __restrict__ ib2,
                                              const float* __restrict__ iw3, const float* __restrict__ ib3,
                                              float* __restrict__ out) {
    __shared__ float xc[108];
    __shared__ float h1[128];
    __shared__ float h2[64];
    int b = blockIdx.x, t = threadIdx.x;
    if (t < 64) xc[t] = ACC[b * 64 + t] * (1.0f / 65536.0f);
    else if (t < 104) xc[t] = env[b * 40 + (t - 64)];
    else if (t < 108) xc[t] = d1d[b * 4 + (t - 104)];
    __syncthreads();
    {
        float a = db1[t];
        for (int k = 0; k < 108; k++) a += xc[k] * dw1[t * 108 + k];
        h1[t] = gelu_f(a);
    }
    __syncthreads();
    if (t < 64) {
        float a = db2[t];
        for (int k = 0; k < 128; k++) a += h1[k] * dw2[t * 128 + k];
        h2[t] = gelu_f(a);
    }
    __syncthreads();
    if (t < 8) {
        float a = db3[t];
        for (int k = 0; k < 64; k++) a += h2[k] * dw3[t * 64 + k];
        out[b * 8 + t] = a;
    }
    __syncthreads();
    {
        float a = ib1[t];
        for (int k = 0; k < 108; k++) a += xc[k] * iw1[t * 108 + k];
        h1[t] = gelu_f(a);
    }
    __syncthreads();
    if (t < 64) {
        float a = ib2[t];
        for (int k = 0; k < 128; k++) a += h1[k] * iw2[t * 128 + k];
        h2[t] = gelu_f(a);
    }
    __syncthreads();
    if (t < 4) {
        float a = ib3[t];
        for (int k = 0; k < 64; k++) a += h2[k] * iw3[t * 64 + k];
        out[128 + b * 4 + t] = a;
    }
}

extern "C" void kernel_launch(void* const* d_in, const int* in_sizes, int n_in,
                              void* d_out, int out_size, void* d_ws, size_t ws_size,
                              hipStream_t stream) {
    const float* grid_  = (const float*)d_in[0];
    const float* env    = (const float*)d_in[1];
    const float* d1d    = (const float*)d_in[2];
    const float* lift_w = (const float*)d_in[3];
    const float* lift_b = (const float*)d_in[4];
    const float* w1r    = (const float*)d_in[5];
    const float* w1i    = (const float*)d_in[6];
    const float* w2r    = (const float*)d_in[7];
    const float* w2i    = (const float*)d_in[8];
    const float* skip_w = (const float*)d_in[9];
    const float* skip_b = (const float*)d_in[10];
    const float* bn_g   = (const float*)d_in[11];
    const float* bn_b   = (const float*)d_in[12];
    const float* bn_m   = (const float*)d_in[13];
    const float* bn_v   = (const float*)d_in[14];
    const float* proj_w = (const float*)d_in[15];
    const float* proj_b = (const float*)d_in[16];
    const float* dw1 = (const float*)d_in[17];
    const float* db1 = (const float*)d_in[18];
    const float* dw2 = (const float*)d_in[19];
    const float* db2 = (const float*)d_in[20];
    const float* dw3 = (const float*)d_in[21];
    const float* db3 = (const float*)d_in[22];
    const float* iw1 = (const float*)d_in[23];
    const float* ib1 = (const float*)d_in[24];
    const float* iw2 = (const float*)d_in[25];
    const float* ib2 = (const float*)d_in[26];
    const float* iw3 = (const float*)d_in[27];
    const float* ib3 = (const float*)d_in[28];

    // Workspace layout (total ~193.3 MB)
    char* ws = (char*)d_ws;
    unsigned short* X   = (unsigned short*)(ws);               // 134,217,728  [b][h][c][w]
    float2* S   = (float2*)(ws + 134217728);                   //  33,554,432 (Y and Z alias; Z = bf16 hi/lo planes)
    float2* XF  = (float2*)(ws + 167772160);                   //   4,194,304
    float2* YF  = (float2*)(ws + 171966464);                   //   4,194,304
    float2* WPK = (float2*)(ws + 176160768);                   //  16,777,216
    float*  ACC = (float*)(ws + 192937984);                    //       4,096
    unsigned short* TfH = (unsigned short*)(ws + 192942080);   //      16,384
    unsigned short* TfL = (unsigned short*)(ws + 192958464);   //      16,384
    unsigned short* TiH = (unsigned short*)(ws + 192974848);   //      16,384
    unsigned short* TiL = (unsigned short*)(ws + 192991232);   //      16,384
    unsigned short* WH  = (unsigned short*)(ws + 193007616);   //      32,768
    unsigned short* WL  = (unsigned short*)(ws + 193040384);   //      32,768
    unsigned short* PH  = (unsigned short*)(ws + 193073152);   //       8,192
    unsigned short* PL  = (unsigned short*)(ws + 193081344);   //       8,192
    // h-DFT MFMA tables (12 x 16,384 B)
    unsigned short* FcH = (unsigned short*)(ws + 193089536);
    unsigned short* FcL = (unsigned short*)(ws + 193105920);
    unsigned short* FsH = (unsigned short*)(ws + 193122304);
    unsigned short* FsL = (unsigned short*)(ws + 193138688);
    unsigned short* FnH = (unsigned short*)(ws + 193155072);
    unsigned short* FnL = (unsigned short*)(ws + 193171456);
    unsigned short* IcH = (unsigned short*)(ws + 193187840);
    unsigned short* IcL = (unsigned short*)(ws + 193204224);
    unsigned short* IsH = (unsigned short*)(ws + 193220608);
    unsigned short* IsL = (unsigned short*)(ws + 193236992);
    unsigned short* InH = (unsigned short*)(ws + 193253376);
    unsigned short* InL = (unsigned short*)(ws + 193269760);
    // lift weights bf16 hi/lo [64][32] (2 x 4,096 B)
    unsigned short* LwH = (unsigned short*)(ws + 193286144);
    unsigned short* LwL = (unsigned short*)(ws + 193290240);   // end 193,294,336

    unsigned short* Zs = (unsigned short*)S;   // Z bf16 hi/lo view (byte-coincident with Y rows)

    hipMemsetAsync(ACC, 0, 1024 * sizeof(float), stream);
    k_prep<<<216, 256, 0, stream>>>(skip_w, bn_g, bn_v, proj_w, lift_w,
                                    TfH, TfL, TiH, TiL, WH, WL, PH, PL,
                                    FcH, FcL, FsH, FsL, FnH, FnL, IcH, IcL, IsH, IsL, InH, InL,
                                    LwH, LwL);
    k_lift<<<8192, 256, 0, stream>>>(grid_, LwH, LwL, lift_b, X, TfH, TfL, S);
    for (int l = 0; l < L_; l++) {
        k_fwd_h<<<1024, 256, 0, stream>>>(S, XF, FcH, FcL, FsH, FsL, FnH, FnL,
                                          w1r, w1i, w2r, w2i, WPK, l);
        k_mix<<<512, 256, 0, stream>>>(XF, WPK, YF);
        k_inv_h<<<1024, 256, 0, stream>>>(YF, Zs, IcH, IcL, IsH, IsL, InH, InL,
                                          bn_g + l * 64, bn_v + l * 64);
        k_tail<<<4096, 256, 0, stream>>>(X, Zs, WH + l * 4096, WL + l * 4096,
                                         skip_b + l * 64, bn_g + l * 64, bn_b + l * 64,
                                         bn_m + l * 64, bn_v + l * 64,
                                         TiH, TiL, TfH, TfL, S, (l < 3) ? 1 : 2,
                                         PH, PL, proj_b, ACC);
    }
    k_head<<<16, 128, 0, stream>>>(ACC, env, d1d, dw1, db1, dw2, db2, dw3, db3,
                                   iw1, ib1, iw2, ib2, iw3, ib3, (float*)d_out);
}